// Round 1
// baseline (2842.966 us; speedup 1.0000x reference)
//
#include <hip/hip_runtime.h>

#define DIM 128

// ---------------------------------------------------------------------------
// GEMM: h[i][j] = sum_k x[i][k] * W[j][k] + b[j]   (h = x @ W^T + b)
// Block = 256 threads, 64 rows of x per block.
// W is staged transposed into LDS: Wt[k][j] = W[j][k]  (128x128 f32 = 64 KiB).
// Thread (colgrp = t&15, rowgrp = t>>4) computes rows r0..r0+3 and cols
// {colgrp*4..+3, 64+colgrp*4..+3}  -> 4x8 register tile, dot over k.
// Per 4-k chunk: 4 global float4 (x) + 8 ds_read_b128 (Wt) + 128 v_fma_f32.
// Wt reads: lane addresses stride 16B across colgrp -> banks colgrp*4, 2-way
// conflict only (free per m136).
// ---------------------------------------------------------------------------
__global__ __launch_bounds__(256, 2) void gemm_xWT(
    const float* __restrict__ x, const float* __restrict__ W,
    const float* __restrict__ b, float* __restrict__ h, int N) {
  __shared__ float Wt[DIM][DIM];

  const int t = threadIdx.x;

  // Stage W transposed. 128 rows x 32 float4 each = 4096 float4, 16/thread.
  for (int i = t; i < DIM * (DIM / 4); i += 256) {
    int j  = i >> 5;          // W row (output col)
    int k4 = (i & 31) << 2;   // k offset
    float4 v = *reinterpret_cast<const float4*>(W + j * DIM + k4);
    Wt[k4 + 0][j] = v.x;
    Wt[k4 + 1][j] = v.y;
    Wt[k4 + 2][j] = v.z;
    Wt[k4 + 3][j] = v.w;
  }
  __syncthreads();

  const int colgrp = t & 15;
  const int rowgrp = t >> 4;
  const int r0 = blockIdx.x * 64 + rowgrp * 4;
  const int j0 = colgrp * 4;

  float acc[4][8];
#pragma unroll
  for (int a = 0; a < 4; ++a)
#pragma unroll
    for (int c = 0; c < 8; ++c) acc[a][c] = 0.0f;

  for (int k4 = 0; k4 < DIM; k4 += 4) {
    float4 xv[4];
#pragma unroll
    for (int rr = 0; rr < 4; ++rr) {
      int r = r0 + rr;
      if (r < N) {
        xv[rr] = *reinterpret_cast<const float4*>(x + (size_t)r * DIM + k4);
      } else {
        xv[rr] = make_float4(0.f, 0.f, 0.f, 0.f);
      }
    }
#pragma unroll
    for (int kk = 0; kk < 4; ++kk) {
      float4 w0 = *reinterpret_cast<const float4*>(&Wt[k4 + kk][j0]);
      float4 w1 = *reinterpret_cast<const float4*>(&Wt[k4 + kk][j0 + 64]);
#pragma unroll
      for (int rr = 0; rr < 4; ++rr) {
        float xk = (kk == 0) ? xv[rr].x : (kk == 1) ? xv[rr].y
                 : (kk == 2) ? xv[rr].z : xv[rr].w;
        acc[rr][0] += xk * w0.x;
        acc[rr][1] += xk * w0.y;
        acc[rr][2] += xk * w0.z;
        acc[rr][3] += xk * w0.w;
        acc[rr][4] += xk * w1.x;
        acc[rr][5] += xk * w1.y;
        acc[rr][6] += xk * w1.z;
        acc[rr][7] += xk * w1.w;
      }
    }
  }

  const float4 bv0 = *reinterpret_cast<const float4*>(b + j0);
  const float4 bv1 = *reinterpret_cast<const float4*>(b + j0 + 64);
#pragma unroll
  for (int rr = 0; rr < 4; ++rr) {
    int r = r0 + rr;
    if (r < N) {
      float4 o0 = make_float4(acc[rr][0] + bv0.x, acc[rr][1] + bv0.y,
                              acc[rr][2] + bv0.z, acc[rr][3] + bv0.w);
      float4 o1 = make_float4(acc[rr][4] + bv1.x, acc[rr][5] + bv1.y,
                              acc[rr][6] + bv1.z, acc[rr][7] + bv1.w);
      *reinterpret_cast<float4*>(h + (size_t)r * DIM + j0)      = o0;
      *reinterpret_cast<float4*>(h + (size_t)r * DIM + j0 + 64) = o1;
    }
  }
}

// ---------------------------------------------------------------------------
// Scatter: for each edge e: out[row[e]][:] += w[e] * h[col[e]][:]
// 32 lanes per edge, float4 per lane -> 4 f32 atomicAdds per lane.
// out already holds x (residual), so this accumulates agg + x in place.
// ---------------------------------------------------------------------------
__global__ __launch_bounds__(256) void scatter_edges(
    const float* __restrict__ h, const int* __restrict__ erow,
    const int* __restrict__ ecol, const float* __restrict__ ew,
    float* __restrict__ out, int E) {
  long long tid = (long long)blockIdx.x * 256 + threadIdx.x;
  int e = (int)(tid >> 5);
  if (e >= E) return;
  int d0 = ((int)tid & 31) << 2;

  int r   = erow[e];
  int c   = ecol[e];
  float w = ew[e];

  float4 v = *reinterpret_cast<const float4*>(h + (size_t)c * DIM + d0);
  float* o = out + (size_t)r * DIM + d0;
  atomicAdd(o + 0, v.x * w);
  atomicAdd(o + 1, v.y * w);
  atomicAdd(o + 2, v.z * w);
  atomicAdd(o + 3, v.w * w);
}

// ---------------------------------------------------------------------------
// Finalize: out = leaky_relu(out, 0.2) in place (out already = agg + x).
// ---------------------------------------------------------------------------
__global__ __launch_bounds__(256) void finalize_lrelu(float* __restrict__ out,
                                                      int n4) {
  int i = blockIdx.x * 256 + threadIdx.x;
  if (i < n4) {
    float4 v = reinterpret_cast<float4*>(out)[i];
    v.x = v.x > 0.f ? v.x : 0.2f * v.x;
    v.y = v.y > 0.f ? v.y : 0.2f * v.y;
    v.z = v.z > 0.f ? v.z : 0.2f * v.z;
    v.w = v.w > 0.f ? v.w : 0.2f * v.w;
    reinterpret_cast<float4*>(out)[i] = v;
  }
}

extern "C" void kernel_launch(void* const* d_in, const int* in_sizes, int n_in,
                              void* d_out, int out_size, void* d_ws,
                              size_t ws_size, hipStream_t stream) {
  const float* x  = (const float*)d_in[0];
  const int* erow = (const int*)d_in[1];
  const int* ecol = (const int*)d_in[2];
  const float* ew = (const float*)d_in[3];
  const float* W  = (const float*)d_in[4];
  const float* b  = (const float*)d_in[5];
  float* out      = (float*)d_out;

  const int N = in_sizes[0] / DIM;
  const int E = in_sizes[1];

  float* h = (float*)d_ws;  // N*DIM floats = 51.2 MB scratch

  // out <- x  (residual base; scatter accumulates on top)
  hipMemcpyAsync(out, x, (size_t)N * DIM * sizeof(float),
                 hipMemcpyDeviceToDevice, stream);

  // h = x @ W^T + b
  int gemm_blocks = (N + 63) / 64;
  gemm_xWT<<<gemm_blocks, 256, 0, stream>>>(x, W, b, h, N);

  // out += scatter-add of w[e] * h[col[e]] into row[e]
  long long sthreads = (long long)E * 32;
  int sblocks = (int)((sthreads + 255) / 256);
  scatter_edges<<<sblocks, 256, 0, stream>>>(h, erow, ecol, ew, out, E);

  // out = leaky_relu(out, 0.2)
  int n4 = N * DIM / 4;
  finalize_lrelu<<<(n4 + 255) / 256, 256, 0, stream>>>(out, n4);
}

// Round 2
// 443.316 us; speedup vs baseline: 6.4130x; 6.4130x over previous
//
#include <hip/hip_runtime.h>

#define DIM 128

// ======================= GEMM: h = x @ W^T + b =============================
__global__ __launch_bounds__(256, 2) void gemm_xWT(
    const float* __restrict__ x, const float* __restrict__ W,
    const float* __restrict__ b, float* __restrict__ h, int N) {
  __shared__ float Wt[DIM][DIM];

  const int t = threadIdx.x;
  for (int i = t; i < DIM * (DIM / 4); i += 256) {
    int j  = i >> 5;
    int k4 = (i & 31) << 2;
    float4 v = *reinterpret_cast<const float4*>(W + j * DIM + k4);
    Wt[k4 + 0][j] = v.x;
    Wt[k4 + 1][j] = v.y;
    Wt[k4 + 2][j] = v.z;
    Wt[k4 + 3][j] = v.w;
  }
  __syncthreads();

  const int colgrp = t & 15;
  const int rowgrp = t >> 4;
  const int r0 = blockIdx.x * 64 + rowgrp * 4;
  const int j0 = colgrp * 4;

  float acc[4][8];
#pragma unroll
  for (int a = 0; a < 4; ++a)
#pragma unroll
    for (int c = 0; c < 8; ++c) acc[a][c] = 0.0f;

  for (int k4 = 0; k4 < DIM; k4 += 4) {
    float4 xv[4];
#pragma unroll
    for (int rr = 0; rr < 4; ++rr) {
      int r = r0 + rr;
      xv[rr] = (r < N) ? *reinterpret_cast<const float4*>(x + (size_t)r * DIM + k4)
                       : make_float4(0.f, 0.f, 0.f, 0.f);
    }
#pragma unroll
    for (int kk = 0; kk < 4; ++kk) {
      float4 w0 = *reinterpret_cast<const float4*>(&Wt[k4 + kk][j0]);
      float4 w1 = *reinterpret_cast<const float4*>(&Wt[k4 + kk][j0 + 64]);
#pragma unroll
      for (int rr = 0; rr < 4; ++rr) {
        float xk = (kk == 0) ? xv[rr].x : (kk == 1) ? xv[rr].y
                 : (kk == 2) ? xv[rr].z : xv[rr].w;
        acc[rr][0] += xk * w0.x; acc[rr][1] += xk * w0.y;
        acc[rr][2] += xk * w0.z; acc[rr][3] += xk * w0.w;
        acc[rr][4] += xk * w1.x; acc[rr][5] += xk * w1.y;
        acc[rr][6] += xk * w1.z; acc[rr][7] += xk * w1.w;
      }
    }
  }

  const float4 bv0 = *reinterpret_cast<const float4*>(b + j0);
  const float4 bv1 = *reinterpret_cast<const float4*>(b + j0 + 64);
#pragma unroll
  for (int rr = 0; rr < 4; ++rr) {
    int r = r0 + rr;
    if (r < N) {
      float4 o0 = make_float4(acc[rr][0] + bv0.x, acc[rr][1] + bv0.y,
                              acc[rr][2] + bv0.z, acc[rr][3] + bv0.w);
      float4 o1 = make_float4(acc[rr][4] + bv1.x, acc[rr][5] + bv1.y,
                              acc[rr][6] + bv1.z, acc[rr][7] + bv1.w);
      *reinterpret_cast<float4*>(h + (size_t)r * DIM + j0)      = o0;
      *reinterpret_cast<float4*>(h + (size_t)r * DIM + j0 + 64) = o1;
    }
  }
}

// ======================= CSR build (device-side) ===========================
// deg[r] = #edges with row==r
__global__ __launch_bounds__(256) void hist_rows(const int* __restrict__ erow,
                                                 int* __restrict__ deg, int E) {
  int e = blockIdx.x * 256 + threadIdx.x;
  if (e < E) atomicAdd(&deg[erow[e]], 1);
}

// Per-1024-element block exclusive scan; block totals to bsum.
__global__ __launch_bounds__(256) void scan_blocks(const int* __restrict__ deg,
                                                   int* __restrict__ off,
                                                   int* __restrict__ bsum, int N) {
  __shared__ int lds[256];
  const int base = blockIdx.x * 1024;
  const int t = threadIdx.x;
  int v[4], s = 0;
#pragma unroll
  for (int i = 0; i < 4; ++i) {
    int idx = base + t * 4 + i;
    v[i] = (idx < N) ? deg[idx] : 0;
    s += v[i];
  }
  lds[t] = s;
  __syncthreads();
  for (int d = 1; d < 256; d <<= 1) {
    int val = (t >= d) ? lds[t - d] : 0;
    __syncthreads();
    lds[t] += val;
    __syncthreads();
  }
  int incl = lds[t];
  int excl = incl - s;
  if (t == 255) bsum[blockIdx.x] = incl;
  int run = excl;
#pragma unroll
  for (int i = 0; i < 4; ++i) {
    int idx = base + t * 4 + i;
    if (idx < N) off[idx] = run;
    run += v[i];
  }
}

// Exclusive scan of block sums (NB <= 256). Single block.
__global__ __launch_bounds__(256) void scan_bsum(int* __restrict__ bsum, int NB) {
  __shared__ int lds[256];
  const int t = threadIdx.x;
  int s = (t < NB) ? bsum[t] : 0;
  lds[t] = s;
  __syncthreads();
  for (int d = 1; d < 256; d <<= 1) {
    int val = (t >= d) ? lds[t - d] : 0;
    __syncthreads();
    lds[t] += val;
    __syncthreads();
  }
  if (t < NB) bsum[t] = lds[t] - s;  // exclusive
}

// off += scanned block base; pos = off (scatter cursors)
__global__ __launch_bounds__(256) void add_base(int* __restrict__ off,
                                                int* __restrict__ pos,
                                                const int* __restrict__ bsum, int N) {
  int i = blockIdx.x * 256 + threadIdx.x;
  if (i < N) {
    int o = off[i] + bsum[i >> 10];
    off[i] = o;
    pos[i] = o;
  }
}

// Place each edge's (col, weight) into its row segment.
__global__ __launch_bounds__(256) void scatter_csr(
    const int* __restrict__ erow, const int* __restrict__ ecol,
    const float* __restrict__ ew, int* __restrict__ pos,
    int2* __restrict__ sedge, int E) {
  int e = blockIdx.x * 256 + threadIdx.x;
  if (e < E) {
    int r = erow[e];
    int p = atomicAdd(&pos[r], 1);
    sedge[p] = make_int2(ecol[e], __float_as_int(ew[e]));
  }
}

// ================== Aggregate: out = lrelu(x + sum_e w*h[col]) =============
// One 64-lane wave per row; float2 per lane covers D=128.
__global__ __launch_bounds__(256) void aggregate(
    const float* __restrict__ h, const float* __restrict__ x,
    const int* __restrict__ off, const int* __restrict__ deg,
    const int2* __restrict__ sedge, float* __restrict__ out, int N) {
  int r = (blockIdx.x * 256 + threadIdx.x) >> 6;
  int lane = threadIdx.x & 63;
  if (r >= N) return;

  const int start = off[r];
  const int n = deg[r];
  float2 acc = make_float2(0.f, 0.f);
#pragma unroll 2
  for (int i = 0; i < n; ++i) {
    int2 e = sedge[start + i];
    float w = __int_as_float(e.y);
    float2 hv = *reinterpret_cast<const float2*>(h + (size_t)e.x * DIM + lane * 2);
    acc.x += w * hv.x;
    acc.y += w * hv.y;
  }
  float2 xv = *reinterpret_cast<const float2*>(x + (size_t)r * DIM + lane * 2);
  float2 o = make_float2(acc.x + xv.x, acc.y + xv.y);
  o.x = o.x > 0.f ? o.x : 0.2f * o.x;
  o.y = o.y > 0.f ? o.y : 0.2f * o.y;
  *reinterpret_cast<float2*>(out + (size_t)r * DIM + lane * 2) = o;
}

// ===========================================================================
extern "C" void kernel_launch(void* const* d_in, const int* in_sizes, int n_in,
                              void* d_out, int out_size, void* d_ws,
                              size_t ws_size, hipStream_t stream) {
  const float* x  = (const float*)d_in[0];
  const int* erow = (const int*)d_in[1];
  const int* ecol = (const int*)d_in[2];
  const float* ew = (const float*)d_in[3];
  const float* W  = (const float*)d_in[4];
  const float* b  = (const float*)d_in[5];
  float* out      = (float*)d_out;

  const int N = in_sizes[0] / DIM;
  const int E = in_sizes[1];
  const int NB = (N + 1023) / 1024;  // scan blocks (<=256 for N<=262144)

  // Workspace layout (16B aligned chunks)
  char* wsp = (char*)d_ws;
  float* h    = (float*)wsp;                       wsp += (size_t)N * DIM * sizeof(float);
  int*   off  = (int*)wsp;                         wsp += (size_t)N * sizeof(int);
  int*   pos  = (int*)wsp;                         wsp += (size_t)N * sizeof(int);
  int*   deg  = (int*)wsp;                         wsp += (size_t)N * sizeof(int);
  int*   bsum = (int*)wsp;                         wsp += 4096;
  int2*  sedge= (int2*)wsp;                        wsp += (size_t)E * sizeof(int2);

  // h = x @ W^T + b
  gemm_xWT<<<(N + 63) / 64, 256, 0, stream>>>(x, W, b, h, N);

  // CSR build
  hipMemsetAsync(deg, 0, (size_t)N * sizeof(int), stream);
  hist_rows<<<(E + 255) / 256, 256, 0, stream>>>(erow, deg, E);
  scan_blocks<<<NB, 256, 0, stream>>>(deg, off, bsum, N);
  scan_bsum<<<1, 256, 0, stream>>>(bsum, NB);
  add_base<<<(N + 255) / 256, 256, 0, stream>>>(off, pos, bsum, N);
  scatter_csr<<<(E + 255) / 256, 256, 0, stream>>>(erow, ecol, ew, pos, sedge, E);

  // Gather-reduce + residual + leaky-relu
  aggregate<<<(N * 64 + 255) / 256, 256, 0, stream>>>(h, x, off, deg, sedge, out, N);
}

// Round 3
// 316.554 us; speedup vs baseline: 8.9810x; 1.4004x over previous
//
#include <hip/hip_runtime.h>

#define DIM 128

typedef short bf16x8 __attribute__((ext_vector_type(8)));
typedef float f32x4  __attribute__((ext_vector_type(4)));

__device__ inline unsigned short f2b(float f) {  // fp32 -> bf16 RNE
  unsigned int u = __float_as_uint(f);
  unsigned int r = u + 0x7FFFu + ((u >> 16) & 1u);
  return (unsigned short)(r >> 16);
}

// ================= W -> bf16 convert (once per launch) =====================
__global__ __launch_bounds__(256) void conv_W(const float* __restrict__ W,
                                              unsigned short* __restrict__ Wb) {
  int i = blockIdx.x * 256 + threadIdx.x;  // 16384 elems
  if (i < DIM * DIM) Wb[i] = f2b(W[i]);
}

// ================= GEMM: hb = bf16(x @ W^T + b), MFMA ======================
// Block = 256 thr = 4 waves; wave w -> rows m0..m0+15, all 128 cols.
// Per wave: 8 n-tiles (16x16), K=128 in 4 steps of 32.
// A frag: lane l holds x[m0+(l&15)][k0+(l>>4)*8 ..+8) (fp32->bf16 inline).
// B frag: lane l holds W[jt*16+(l&15)][k0+(l>>4)*8 ..+8) (bf16, L2-resident).
// C/D: col=l&15, row=(l>>4)*4+reg (m89-verified).
__global__ __launch_bounds__(256) void gemm_mfma(
    const float* __restrict__ x, const unsigned short* __restrict__ Wb,
    const float* __restrict__ b, unsigned short* __restrict__ hb, int N) {
  const int wid  = threadIdx.x >> 6;
  const int lane = threadIdx.x & 63;
  const int m0   = blockIdx.x * 64 + wid * 16;
  const int mrow = m0 + (lane & 15);
  const int koff = (lane >> 4) * 8;
  const int arow = (mrow < N) ? mrow : 0;  // clamp; stores guarded below

  f32x4 acc[8];
#pragma unroll
  for (int j = 0; j < 8; ++j) acc[j] = (f32x4){0.f, 0.f, 0.f, 0.f};

#pragma unroll
  for (int k0 = 0; k0 < DIM; k0 += 32) {
    const float* xp = x + (size_t)arow * DIM + k0 + koff;
    float4 a0 = *reinterpret_cast<const float4*>(xp);
    float4 a1 = *reinterpret_cast<const float4*>(xp + 4);
    bf16x8 af;
    af[0] = (short)f2b(a0.x); af[1] = (short)f2b(a0.y);
    af[2] = (short)f2b(a0.z); af[3] = (short)f2b(a0.w);
    af[4] = (short)f2b(a1.x); af[5] = (short)f2b(a1.y);
    af[6] = (short)f2b(a1.z); af[7] = (short)f2b(a1.w);
#pragma unroll
    for (int j = 0; j < 8; ++j) {
      const unsigned short* wp = Wb + (size_t)(j * 16 + (lane & 15)) * DIM + k0 + koff;
      bf16x8 bf = *reinterpret_cast<const bf16x8*>(wp);
      acc[j] = __builtin_amdgcn_mfma_f32_16x16x32_bf16(af, bf, acc[j], 0, 0, 0);
    }
  }

  const int rowbase = (lane >> 4) * 4;
#pragma unroll
  for (int j = 0; j < 8; ++j) {
    int n = j * 16 + (lane & 15);
    float bias = b[n];
#pragma unroll
    for (int i = 0; i < 4; ++i) {
      int m = m0 + rowbase + i;
      if (m < N) hb[(size_t)m * DIM + n] = f2b(acc[j][i] + bias);
    }
  }
}

// ======================= CSR build (device-side) ===========================
__global__ __launch_bounds__(256) void hist_rows(const int* __restrict__ erow,
                                                 int* __restrict__ deg, int E) {
  int e = blockIdx.x * 256 + threadIdx.x;
  if (e < E) atomicAdd(&deg[erow[e]], 1);
}

__global__ __launch_bounds__(256) void scan_blocks(const int* __restrict__ deg,
                                                   int* __restrict__ off,
                                                   int* __restrict__ bsum, int N) {
  __shared__ int lds[256];
  const int base = blockIdx.x * 1024;
  const int t = threadIdx.x;
  int v[4], s = 0;
#pragma unroll
  for (int i = 0; i < 4; ++i) {
    int idx = base + t * 4 + i;
    v[i] = (idx < N) ? deg[idx] : 0;
    s += v[i];
  }
  lds[t] = s;
  __syncthreads();
  for (int d = 1; d < 256; d <<= 1) {
    int val = (t >= d) ? lds[t - d] : 0;
    __syncthreads();
    lds[t] += val;
    __syncthreads();
  }
  int incl = lds[t];
  int excl = incl - s;
  if (t == 255) bsum[blockIdx.x] = incl;
  int run = excl;
#pragma unroll
  for (int i = 0; i < 4; ++i) {
    int idx = base + t * 4 + i;
    if (idx < N) off[idx] = run;
    run += v[i];
  }
}

__global__ __launch_bounds__(256) void scan_bsum(int* __restrict__ bsum, int NB) {
  __shared__ int lds[256];
  const int t = threadIdx.x;
  int s = (t < NB) ? bsum[t] : 0;
  lds[t] = s;
  __syncthreads();
  for (int d = 1; d < 256; d <<= 1) {
    int val = (t >= d) ? lds[t - d] : 0;
    __syncthreads();
    lds[t] += val;
    __syncthreads();
  }
  if (t < NB) bsum[t] = lds[t] - s;  // exclusive
}

__global__ __launch_bounds__(256) void add_base(int* __restrict__ off,
                                                int* __restrict__ pos,
                                                const int* __restrict__ bsum, int N) {
  int i = blockIdx.x * 256 + threadIdx.x;
  if (i < N) {
    int o = off[i] + bsum[i >> 10];
    off[i] = o;
    pos[i] = o;
  }
}

__global__ __launch_bounds__(256) void scatter_csr(
    const int* __restrict__ erow, const int* __restrict__ ecol,
    const float* __restrict__ ew, int* __restrict__ pos,
    int2* __restrict__ sedge, int E) {
  int e = blockIdx.x * 256 + threadIdx.x;
  if (e < E) {
    int r = erow[e];
    int p = atomicAdd(&pos[r], 1);
    sedge[p] = make_int2(ecol[e], __float_as_int(ew[e]));
  }
}

// ============ Aggregate: out = lrelu(x + sum_e w*hb[col]) ==================
// One 64-lane wave per row; 2 bf16 (one dword) per lane covers D=128.
__global__ __launch_bounds__(256) void aggregate(
    const unsigned short* __restrict__ hb, const float* __restrict__ x,
    const int* __restrict__ off, const int* __restrict__ deg,
    const int2* __restrict__ sedge, float* __restrict__ out, int N) {
  int r = (blockIdx.x * 256 + threadIdx.x) >> 6;
  int lane = threadIdx.x & 63;
  if (r >= N) return;

  const int start = off[r];
  const int n = deg[r];
  float2 acc = make_float2(0.f, 0.f);
#pragma unroll 4
  for (int i = 0; i < n; ++i) {
    int2 e = sedge[start + i];
    float w = __int_as_float(e.y);
    unsigned int hv = *reinterpret_cast<const unsigned int*>(
        hb + (size_t)e.x * DIM + lane * 2);
    float h0 = __uint_as_float((hv & 0xFFFFu) << 16);
    float h1 = __uint_as_float((hv >> 16) << 16);
    acc.x += w * h0;
    acc.y += w * h1;
  }
  float2 xv = *reinterpret_cast<const float2*>(x + (size_t)r * DIM + lane * 2);
  float2 o = make_float2(acc.x + xv.x, acc.y + xv.y);
  o.x = o.x > 0.f ? o.x : 0.2f * o.x;
  o.y = o.y > 0.f ? o.y : 0.2f * o.y;
  *reinterpret_cast<float2*>(out + (size_t)r * DIM + lane * 2) = o;
}

// ===========================================================================
extern "C" void kernel_launch(void* const* d_in, const int* in_sizes, int n_in,
                              void* d_out, int out_size, void* d_ws,
                              size_t ws_size, hipStream_t stream) {
  const float* x  = (const float*)d_in[0];
  const int* erow = (const int*)d_in[1];
  const int* ecol = (const int*)d_in[2];
  const float* ew = (const float*)d_in[3];
  const float* W  = (const float*)d_in[4];
  const float* b  = (const float*)d_in[5];
  float* out      = (float*)d_out;

  const int N = in_sizes[0] / DIM;
  const int E = in_sizes[1];
  const int NB = (N + 1023) / 1024;

  // Workspace layout (16B aligned chunks)
  char* wsp = (char*)d_ws;
  unsigned short* hb = (unsigned short*)wsp;  wsp += (size_t)N * DIM * sizeof(unsigned short);
  int*   off  = (int*)wsp;                    wsp += (size_t)N * sizeof(int);
  int*   pos  = (int*)wsp;                    wsp += (size_t)N * sizeof(int);
  int*   deg  = (int*)wsp;                    wsp += (size_t)N * sizeof(int);
  int*   bsum = (int*)wsp;                    wsp += 4096;
  unsigned short* Wb = (unsigned short*)wsp;  wsp += DIM * DIM * sizeof(unsigned short);
  int2*  sedge= (int2*)wsp;                   wsp += (size_t)E * sizeof(int2);

  // W -> bf16
  conv_W<<<(DIM * DIM + 255) / 256, 256, 0, stream>>>(W, Wb);

  // hb = bf16(x @ W^T + b)
  gemm_mfma<<<(N + 63) / 64, 256, 0, stream>>>(x, Wb, b, hb, N);

  // CSR build
  hipMemsetAsync(deg, 0, (size_t)N * sizeof(int), stream);
  hist_rows<<<(E + 255) / 256, 256, 0, stream>>>(erow, deg, E);
  scan_blocks<<<NB, 256, 0, stream>>>(deg, off, bsum, N);
  scan_bsum<<<1, 256, 0, stream>>>(bsum, NB);
  add_base<<<(N + 255) / 256, 256, 0, stream>>>(off, pos, bsum, N);
  scatter_csr<<<(E + 255) / 256, 256, 0, stream>>>(erow, ecol, ew, pos, sedge, E);

  // Gather-reduce + residual + leaky-relu
  aggregate<<<(N * 64 + 255) / 256, 256, 0, stream>>>(hb, x, off, deg, sedge, out, N);
}